// Round 2
// baseline (1215.923 us; speedup 1.0000x reference)
//
#include <hip/hip_runtime.h>

// Problem constants: x [32,3,512,512] fp32, 30 Perona-Malik iterations.
#define BATCH 32
#define HGT 512
#define WID 512
#define PLANE (HGT * WID)            // 262144
#define NPIX (BATCH * PLANE)         // 8388608
#define BSTRIDE (3 * PLANE)          // batch stride in x and d_out
#define NQUAD (NPIX / 4)             // 4 pixels per thread

// ---------------------------------------------------------------------------
// Helpers
// ---------------------------------------------------------------------------
__device__ __forceinline__ float4 ld4(const float* p) {
    return *reinterpret_cast<const float4*>(p);
}
__device__ __forceinline__ void st4(float* p, float4 v) {
    *reinterpret_cast<float4*>(p) = v;
}

// Load the 3 stencil rows (6 wide) for the quad at (h, w0). OOB -> 0
// (matches conv zero padding: nabla = 0 - center there).
__device__ __forceinline__ void pm_rows(const float* __restrict__ ub, int h, int w0,
                                        float rowU[6], float rowM[6], float rowD[6]) {
    const int base = h * WID + w0;
    const bool hn = (h > 0), hs = (h < HGT - 1);
    const bool wl = (w0 > 0), wr = (w0 + 4 < WID);

    float4 um = ld4(ub + base);
    float4 uu = hn ? ld4(ub + base - WID) : make_float4(0.f, 0.f, 0.f, 0.f);
    float4 ud = hs ? ld4(ub + base + WID) : make_float4(0.f, 0.f, 0.f, 0.f);

    rowM[0] = wl ? ub[base - 1] : 0.f;
    rowM[1] = um.x; rowM[2] = um.y; rowM[3] = um.z; rowM[4] = um.w;
    rowM[5] = wr ? ub[base + 4] : 0.f;

    rowU[0] = (hn && wl) ? ub[base - WID - 1] : 0.f;
    rowU[1] = uu.x; rowU[2] = uu.y; rowU[3] = uu.z; rowU[4] = uu.w;
    rowU[5] = (hn && wr) ? ub[base - WID + 4] : 0.f;

    rowD[0] = (hs && wl) ? ub[base + WID - 1] : 0.f;
    rowD[1] = ud.x; rowD[2] = ud.y; rowD[3] = ud.z; rowD[4] = ud.w;
    rowD[5] = (hs && wr) ? ub[base + WID + 4] : 0.f;
}

// One Perona-Malik update for the 4 pixels of the quad.
__device__ __forceinline__ float4 pm_compute(const float rowU[6], const float rowM[6],
                                             const float rowD[6], float delta, float inv_k2) {
    float res[4];
#pragma unroll
    for (int j = 0; j < 4; ++j) {
        const float c = rowM[j + 1];
        float upd = 0.f;
#define ACC(nb, wgt) { float d = (nb) - c; float g = 1.f / (1.f + d * d * inv_k2); \
                       upd += (wgt) * g * d; }
        ACC(rowU[j + 1], 1.0f);   // N
        ACC(rowD[j + 1], 1.0f);   // S
        ACC(rowM[j + 2], 1.0f);   // E
        ACC(rowM[j],     1.0f);   // W
        ACC(rowU[j + 2], 0.5f);   // NE
        ACC(rowD[j + 2], 0.5f);   // SE
        ACC(rowD[j],     0.5f);   // SW
        ACC(rowU[j],     0.5f);   // NW
#undef ACC
        res[j] = c + delta * upd;
    }
    return make_float4(res[0], res[1], res[2], res[3]);
}

// ---------------------------------------------------------------------------
// Kernel 1: RGB -> luminance (vectorized). u batch stride = ubs.
// ---------------------------------------------------------------------------
__global__ void lum_v4(const float* __restrict__ x, float* __restrict__ u, int ubs) {
    int idx = blockIdx.x * blockDim.x + threadIdx.x;
    if (idx >= NQUAD) return;
    int b = idx / (PLANE / 4);
    int off = (idx - b * (PLANE / 4)) * 4;
    const float* xb = x + (size_t)b * BSTRIDE + off;
    float4 r = ld4(xb);
    float4 g = ld4(xb + PLANE);
    float4 bl = ld4(xb + 2 * PLANE);
    float4 v;
    v.x = 0.299f * r.x + 0.587f * g.x + 0.114f * bl.x;
    v.y = 0.299f * r.y + 0.587f * g.y + 0.114f * bl.y;
    v.z = 0.299f * r.z + 0.587f * g.z + 0.114f * bl.z;
    v.w = 0.299f * r.w + 0.587f * g.w + 0.114f * bl.w;
    st4(u + (size_t)b * ubs + off, v);
}

// ---------------------------------------------------------------------------
// Kernel 2: one PM diffusion step (vectorized), uin/uout batch stride ubs.
// ---------------------------------------------------------------------------
__global__ void pm_step_v4(const float* __restrict__ uin, float* __restrict__ uout, int ubs,
                           const float* __restrict__ pdelta,
                           const float* __restrict__ pkappa) {
    int idx = blockIdx.x * blockDim.x + threadIdx.x;
    if (idx >= NQUAD) return;
    int b = idx / (PLANE / 4);
    int r4 = idx - b * (PLANE / 4);
    int h = r4 / (WID / 4);
    int w0 = (r4 - h * (WID / 4)) * 4;

    const float* ub = uin + (size_t)b * ubs;
    float rowU[6], rowM[6], rowD[6];
    pm_rows(ub, h, w0, rowU, rowM, rowD);

    float delta = *pdelta;
    float kappa = *pkappa;
    float inv_k2 = 1.f / (kappa * kappa);

    float4 res = pm_compute(rowU, rowM, rowD, delta, inv_k2);
    st4(uout + (size_t)b * ubs + h * WID + w0, res);
}

// ---------------------------------------------------------------------------
// Kernel 3: final PM step fused with channel expand; writes d_out (write-only).
// ---------------------------------------------------------------------------
__global__ void pm_step_expand_v4(const float* __restrict__ uin, int ubs,
                                  float* __restrict__ out,
                                  const float* __restrict__ pdelta,
                                  const float* __restrict__ pkappa,
                                  const float* __restrict__ Wexp,
                                  const float* __restrict__ bexp) {
    int idx = blockIdx.x * blockDim.x + threadIdx.x;
    if (idx >= NQUAD) return;
    int b = idx / (PLANE / 4);
    int r4 = idx - b * (PLANE / 4);
    int h = r4 / (WID / 4);
    int w0 = (r4 - h * (WID / 4)) * 4;

    const float* ub = uin + (size_t)b * ubs;
    float rowU[6], rowM[6], rowD[6];
    pm_rows(ub, h, w0, rowU, rowM, rowD);

    float delta = *pdelta;
    float kappa = *pkappa;
    float inv_k2 = 1.f / (kappa * kappa);

    float4 u30 = pm_compute(rowU, rowM, rowD, delta, inv_k2);

    float s0 = Wexp[0] + Wexp[1] + Wexp[2];
    float s1 = Wexp[3] + Wexp[4] + Wexp[5];
    float s2 = Wexp[6] + Wexp[7] + Wexp[8];
    float b0 = bexp[0], b1 = bexp[1], b2 = bexp[2];

    size_t ob = (size_t)b * BSTRIDE + h * WID + w0;
    st4(out + ob,
        make_float4(s0 * u30.x + b0, s0 * u30.y + b0, s0 * u30.z + b0, s0 * u30.w + b0));
    st4(out + ob + PLANE,
        make_float4(s1 * u30.x + b1, s1 * u30.y + b1, s1 * u30.z + b1, s1 * u30.w + b1));
    st4(out + ob + 2 * PLANE,
        make_float4(s2 * u30.x + b2, s2 * u30.y + b2, s2 * u30.z + b2, s2 * u30.w + b2));
}

// ---------------------------------------------------------------------------
// Fallback expand (only used if ws too small): reads own pixel from plane 0,
// writes 3 planes. (Round-0 scheme.)
// ---------------------------------------------------------------------------
__global__ void expand_own_v4(float* __restrict__ out,
                              const float* __restrict__ Wexp,
                              const float* __restrict__ bexp) {
    int idx = blockIdx.x * blockDim.x + threadIdx.x;
    if (idx >= NQUAD) return;
    int b = idx / (PLANE / 4);
    int off = (idx - b * (PLANE / 4)) * 4;
    size_t base = (size_t)b * BSTRIDE + off;

    float4 u = ld4(out + base);
    float s0 = Wexp[0] + Wexp[1] + Wexp[2];
    float s1 = Wexp[3] + Wexp[4] + Wexp[5];
    float s2 = Wexp[6] + Wexp[7] + Wexp[8];
    float b0 = bexp[0], b1 = bexp[1], b2 = bexp[2];

    st4(out + base, make_float4(s0 * u.x + b0, s0 * u.y + b0, s0 * u.z + b0, s0 * u.w + b0));
    st4(out + base + PLANE,
        make_float4(s1 * u.x + b1, s1 * u.y + b1, s1 * u.z + b1, s1 * u.w + b1));
    st4(out + base + 2 * PLANE,
        make_float4(s2 * u.x + b2, s2 * u.y + b2, s2 * u.z + b2, s2 * u.w + b2));
}

extern "C" void kernel_launch(void* const* d_in, const int* in_sizes, int n_in,
                              void* d_out, int out_size, void* d_ws, size_t ws_size,
                              hipStream_t stream) {
    const float* x      = (const float*)d_in[0];
    const float* pdelta = (const float*)d_in[1];
    const float* pkappa = (const float*)d_in[2];
    const float* Wexp   = (const float*)d_in[3];
    const float* bexp   = (const float*)d_in[4];
    float* out = (float*)d_out;

    const int block = 256;
    const int grid = (NQUAD + block - 1) / block;   // 8192 blocks

    const size_t need = (size_t)2 * NPIX * sizeof(float);   // 64 MB
    if (ws_size >= need) {
        // Scratch ping-pong in d_ws (dense [32,512,512] planes); d_out is
        // written exactly once, by the fused final step.
        float* uA = (float*)d_ws;
        float* uB = uA + NPIX;
        lum_v4<<<grid, block, 0, stream>>>(x, uA, PLANE);
        float* src = uA;
        float* dst = uB;
        for (int k = 0; k < 29; ++k) {
            pm_step_v4<<<grid, block, 0, stream>>>(src, dst, PLANE, pdelta, pkappa);
            float* t = src; src = dst; dst = t;
        }
        // After 29 steps u29 is in src (== uB). Final step fused with expand.
        pm_step_expand_v4<<<grid, block, 0, stream>>>(src, PLANE, out,
                                                      pdelta, pkappa, Wexp, bexp);
    } else {
        // Fallback: ping-pong in d_out planes 0/1 (batch stride BSTRIDE).
        float* uA = out;
        float* uB = out + PLANE;
        lum_v4<<<grid, block, 0, stream>>>(x, uA, BSTRIDE);
        float* src = uA;
        float* dst = uB;
        for (int k = 0; k < 30; ++k) {
            pm_step_v4<<<grid, block, 0, stream>>>(src, dst, BSTRIDE, pdelta, pkappa);
            float* t = src; src = dst; dst = t;
        }
        expand_own_v4<<<grid, block, 0, stream>>>(out, Wexp, bexp);
    }
}

// Round 3
// 668.237 us; speedup vs baseline: 1.8196x; 1.8196x over previous
//
#include <hip/hip_runtime.h>

// Problem constants: x [32,3,512,512] fp32, 30 Perona-Malik iterations.
#define BATCH 32
#define HGT 512
#define WID 512
#define PLANE (HGT * WID)            // 262144
#define NPIX (BATCH * PLANE)         // 8388608
#define BSTRIDE (3 * PLANE)          // batch stride in x and d_out
#define NQUAD (NPIX / 4)             // 4 pixels per thread

// ---------------------------------------------------------------------------
// Helpers
// ---------------------------------------------------------------------------
__device__ __forceinline__ float4 ld4(const float* p) {
    return *reinterpret_cast<const float4*>(p);
}
__device__ __forceinline__ void st4(float* p, float4 v) {
    *reinterpret_cast<float4*>(p) = v;
}

// Load the 3 stencil rows (6 wide) for the quad at (h, w0). OOB -> 0
// (matches conv zero padding: nabla = 0 - center there).
__device__ __forceinline__ void pm_rows(const float* __restrict__ ub, int h, int w0,
                                        float rowU[6], float rowM[6], float rowD[6]) {
    const int base = h * WID + w0;
    const bool hn = (h > 0), hs = (h < HGT - 1);
    const bool wl = (w0 > 0), wr = (w0 + 4 < WID);

    float4 um = ld4(ub + base);
    float4 uu = hn ? ld4(ub + base - WID) : make_float4(0.f, 0.f, 0.f, 0.f);
    float4 ud = hs ? ld4(ub + base + WID) : make_float4(0.f, 0.f, 0.f, 0.f);

    rowM[0] = wl ? ub[base - 1] : 0.f;
    rowM[1] = um.x; rowM[2] = um.y; rowM[3] = um.z; rowM[4] = um.w;
    rowM[5] = wr ? ub[base + 4] : 0.f;

    rowU[0] = (hn && wl) ? ub[base - WID - 1] : 0.f;
    rowU[1] = uu.x; rowU[2] = uu.y; rowU[3] = uu.z; rowU[4] = uu.w;
    rowU[5] = (hn && wr) ? ub[base - WID + 4] : 0.f;

    rowD[0] = (hs && wl) ? ub[base + WID - 1] : 0.f;
    rowD[1] = ud.x; rowD[2] = ud.y; rowD[3] = ud.z; rowD[4] = ud.w;
    rowD[5] = (hs && wr) ? ub[base + WID + 4] : 0.f;
}

// One Perona-Malik update for the 4 pixels of the quad.
// Fast path: g = v_rcp_f32(1 + d^2/k^2) -- ~1 ulp, far inside the 8.9e-3
// absolute correctness threshold; avoids the ~10-instr IEEE div sequence.
__device__ __forceinline__ float4 pm_compute(const float rowU[6], const float rowM[6],
                                             const float rowD[6], float delta, float inv_k2) {
    float res[4];
#pragma unroll
    for (int j = 0; j < 4; ++j) {
        const float c = rowM[j + 1];
        float upd = 0.f;
#define ACC(nb, wgt) { float d = (nb) - c;                                   \
                       float g = __builtin_amdgcn_rcpf(fmaf(d * d, inv_k2, 1.f)); \
                       upd = fmaf((wgt) * g, d, upd); }
        ACC(rowU[j + 1], 1.0f);   // N
        ACC(rowD[j + 1], 1.0f);   // S
        ACC(rowM[j + 2], 1.0f);   // E
        ACC(rowM[j],     1.0f);   // W
        ACC(rowU[j + 2], 0.5f);   // NE
        ACC(rowD[j + 2], 0.5f);   // SE
        ACC(rowD[j],     0.5f);   // SW
        ACC(rowU[j],     0.5f);   // NW
#undef ACC
        res[j] = fmaf(delta, upd, c);
    }
    return make_float4(res[0], res[1], res[2], res[3]);
}

// ---------------------------------------------------------------------------
// Kernel 1: RGB -> luminance (vectorized). u batch stride = ubs.
// ---------------------------------------------------------------------------
__global__ void lum_v4(const float* __restrict__ x, float* __restrict__ u, int ubs) {
    int idx = blockIdx.x * blockDim.x + threadIdx.x;
    if (idx >= NQUAD) return;
    int b = idx / (PLANE / 4);
    int off = (idx - b * (PLANE / 4)) * 4;
    const float* xb = x + (size_t)b * BSTRIDE + off;
    float4 r = ld4(xb);
    float4 g = ld4(xb + PLANE);
    float4 bl = ld4(xb + 2 * PLANE);
    float4 v;
    v.x = 0.299f * r.x + 0.587f * g.x + 0.114f * bl.x;
    v.y = 0.299f * r.y + 0.587f * g.y + 0.114f * bl.y;
    v.z = 0.299f * r.z + 0.587f * g.z + 0.114f * bl.z;
    v.w = 0.299f * r.w + 0.587f * g.w + 0.114f * bl.w;
    st4(u + (size_t)b * ubs + off, v);
}

// ---------------------------------------------------------------------------
// Kernel 2: one PM diffusion step (vectorized), uin/uout batch stride ubs.
// ---------------------------------------------------------------------------
__global__ void pm_step_v4(const float* __restrict__ uin, float* __restrict__ uout, int ubs,
                           const float* __restrict__ pdelta,
                           const float* __restrict__ pkappa) {
    int idx = blockIdx.x * blockDim.x + threadIdx.x;
    if (idx >= NQUAD) return;
    int b = idx / (PLANE / 4);
    int r4 = idx - b * (PLANE / 4);
    int h = r4 / (WID / 4);
    int w0 = (r4 - h * (WID / 4)) * 4;

    const float* ub = uin + (size_t)b * ubs;
    float rowU[6], rowM[6], rowD[6];
    pm_rows(ub, h, w0, rowU, rowM, rowD);

    float delta = *pdelta;
    float kappa = *pkappa;
    float inv_k2 = __builtin_amdgcn_rcpf(kappa * kappa);

    float4 res = pm_compute(rowU, rowM, rowD, delta, inv_k2);
    st4(uout + (size_t)b * ubs + h * WID + w0, res);
}

// ---------------------------------------------------------------------------
// Kernel 3: final PM step fused with channel expand; writes d_out (write-only).
// ---------------------------------------------------------------------------
__global__ void pm_step_expand_v4(const float* __restrict__ uin, int ubs,
                                  float* __restrict__ out,
                                  const float* __restrict__ pdelta,
                                  const float* __restrict__ pkappa,
                                  const float* __restrict__ Wexp,
                                  const float* __restrict__ bexp) {
    int idx = blockIdx.x * blockDim.x + threadIdx.x;
    if (idx >= NQUAD) return;
    int b = idx / (PLANE / 4);
    int r4 = idx - b * (PLANE / 4);
    int h = r4 / (WID / 4);
    int w0 = (r4 - h * (WID / 4)) * 4;

    const float* ub = uin + (size_t)b * ubs;
    float rowU[6], rowM[6], rowD[6];
    pm_rows(ub, h, w0, rowU, rowM, rowD);

    float delta = *pdelta;
    float kappa = *pkappa;
    float inv_k2 = __builtin_amdgcn_rcpf(kappa * kappa);

    float4 u30 = pm_compute(rowU, rowM, rowD, delta, inv_k2);

    float s0 = Wexp[0] + Wexp[1] + Wexp[2];
    float s1 = Wexp[3] + Wexp[4] + Wexp[5];
    float s2 = Wexp[6] + Wexp[7] + Wexp[8];
    float b0 = bexp[0], b1 = bexp[1], b2 = bexp[2];

    size_t ob = (size_t)b * BSTRIDE + h * WID + w0;
    st4(out + ob,
        make_float4(s0 * u30.x + b0, s0 * u30.y + b0, s0 * u30.z + b0, s0 * u30.w + b0));
    st4(out + ob + PLANE,
        make_float4(s1 * u30.x + b1, s1 * u30.y + b1, s1 * u30.z + b1, s1 * u30.w + b1));
    st4(out + ob + 2 * PLANE,
        make_float4(s2 * u30.x + b2, s2 * u30.y + b2, s2 * u30.z + b2, s2 * u30.w + b2));
}

// ---------------------------------------------------------------------------
// Fallback expand (only used if ws too small): reads own pixel from plane 0,
// writes 3 planes.
// ---------------------------------------------------------------------------
__global__ void expand_own_v4(float* __restrict__ out,
                              const float* __restrict__ Wexp,
                              const float* __restrict__ bexp) {
    int idx = blockIdx.x * blockDim.x + threadIdx.x;
    if (idx >= NQUAD) return;
    int b = idx / (PLANE / 4);
    int off = (idx - b * (PLANE / 4)) * 4;
    size_t base = (size_t)b * BSTRIDE + off;

    float4 u = ld4(out + base);
    float s0 = Wexp[0] + Wexp[1] + Wexp[2];
    float s1 = Wexp[3] + Wexp[4] + Wexp[5];
    float s2 = Wexp[6] + Wexp[7] + Wexp[8];
    float b0 = bexp[0], b1 = bexp[1], b2 = bexp[2];

    st4(out + base, make_float4(s0 * u.x + b0, s0 * u.y + b0, s0 * u.z + b0, s0 * u.w + b0));
    st4(out + base + PLANE,
        make_float4(s1 * u.x + b1, s1 * u.y + b1, s1 * u.z + b1, s1 * u.w + b1));
    st4(out + base + 2 * PLANE,
        make_float4(s2 * u.x + b2, s2 * u.y + b2, s2 * u.z + b2, s2 * u.w + b2));
}

extern "C" void kernel_launch(void* const* d_in, const int* in_sizes, int n_in,
                              void* d_out, int out_size, void* d_ws, size_t ws_size,
                              hipStream_t stream) {
    const float* x      = (const float*)d_in[0];
    const float* pdelta = (const float*)d_in[1];
    const float* pkappa = (const float*)d_in[2];
    const float* Wexp   = (const float*)d_in[3];
    const float* bexp   = (const float*)d_in[4];
    float* out = (float*)d_out;

    const int block = 256;
    const int grid = (NQUAD + block - 1) / block;   // 8192 blocks

    const size_t need = (size_t)2 * NPIX * sizeof(float);   // 64 MB
    if (ws_size >= need) {
        // Scratch ping-pong in d_ws (dense [32,512,512] planes); d_out is
        // written exactly once, by the fused final step.
        float* uA = (float*)d_ws;
        float* uB = uA + NPIX;
        lum_v4<<<grid, block, 0, stream>>>(x, uA, PLANE);
        float* src = uA;
        float* dst = uB;
        for (int k = 0; k < 29; ++k) {
            pm_step_v4<<<grid, block, 0, stream>>>(src, dst, PLANE, pdelta, pkappa);
            float* t = src; src = dst; dst = t;
        }
        // After 29 steps u29 is in src. Final step fused with expand.
        pm_step_expand_v4<<<grid, block, 0, stream>>>(src, PLANE, out,
                                                      pdelta, pkappa, Wexp, bexp);
    } else {
        // Fallback: ping-pong in d_out planes 0/1 (batch stride BSTRIDE).
        float* uA = out;
        float* uB = out + PLANE;
        lum_v4<<<grid, block, 0, stream>>>(x, uA, BSTRIDE);
        float* src = uA;
        float* dst = uB;
        for (int k = 0; k < 30; ++k) {
            pm_step_v4<<<grid, block, 0, stream>>>(src, dst, BSTRIDE, pdelta, pkappa);
            float* t = src; src = dst; dst = t;
        }
        expand_own_v4<<<grid, block, 0, stream>>>(out, Wexp, bexp);
    }
}

// Round 4
// 447.883 us; speedup vs baseline: 2.7148x; 1.4920x over previous
//
#include <hip/hip_runtime.h>

// Problem constants: x [32,3,512,512] fp32, 30 Perona-Malik iterations.
#define BATCH 32
#define HGT 512
#define WID 512
#define PLANE (HGT * WID)            // 262144
#define NPIX (BATCH * PLANE)         // 8388608
#define BSTRIDE (3 * PLANE)          // batch stride in x and d_out
#define NQUAD (NPIX / 4)

// Strip decomposition: each thread owns RSTRIP rows x 4 cols.
#define RSTRIP 8
#define STRIPS_H (HGT / RSTRIP)          // 64
#define WQ (WID / 4)                     // 128
#define NSTRIPS (BATCH * STRIPS_H * WQ)  // 262144 threads

__device__ __forceinline__ float4 ld4(const float* p) {
    return *reinterpret_cast<const float4*>(p);
}
__device__ __forceinline__ void st4(float* p, float4 v) {
    *reinterpret_cast<float4*>(p) = v;
}

// phi(d) = g(d)*d = d / (1 + d^2/k^2). g is EVEN in d, so the flux on an
// undirected edge is shared by its two pixels with opposite signs.
__device__ __forceinline__ float pm_flux(float d, float inv_k2) {
    return d * __builtin_amdgcn_rcpf(fmaf(d * d, inv_k2, 1.f));
}

// Load a 6-wide row segment: index k <-> column (w0-1+k). OOB -> 0
// (zero padding: nabla = 0 - center there).
__device__ __forceinline__ void load_row6(const float* __restrict__ ub, int h, int w0,
                                          float r[6]) {
    const int base = h * WID + w0;
    float4 v = ld4(ub + base);
    r[1] = v.x; r[2] = v.y; r[3] = v.z; r[4] = v.w;
    r[0] = (w0 > 0) ? ub[base - 1] : 0.f;
    r[5] = (w0 + 4 < WID) ? ub[base + 4] : 0.f;
}

// Shared fluxes between upper row a and lower row b (6-wide segments).
//  vF[j]  = phi(b[j+1]-a[j+1])  vertical  edge, col w0+j
//  seF[i] = phi(b[i+1]-a[i])    SE-going  edge, upper col w0-1+i -> lower +1
//  swF[i] = phi(b[i]-a[i+1])    SW-going  edge, upper col w0+i   -> lower -1
__device__ __forceinline__ void level_flux(const float a[6], const float b[6],
                                           float vF[4], float seF[5], float swF[5],
                                           float inv_k2) {
#pragma unroll
    for (int j = 0; j < 4; ++j) vF[j] = pm_flux(b[j + 1] - a[j + 1], inv_k2);
#pragma unroll
    for (int i = 0; i < 5; ++i) seF[i] = pm_flux(b[i + 1] - a[i], inv_k2);
#pragma unroll
    for (int i = 0; i < 5; ++i) swF[i] = pm_flux(b[i] - a[i + 1], inv_k2);
}

// Core strip computation. Computes the 4 output pixels of each of the RSTRIP
// rows and hands them to EMIT(h, float4).
template <typename Emit>
__device__ __forceinline__ void pm_strip(const float* __restrict__ ub, int h0, int w0,
                                         float delta, float inv_k2, Emit&& emit) {
    float a[6], m[6], d[6];
    if (h0 > 0) load_row6(ub, h0 - 1, w0, a);
    else {
#pragma unroll
        for (int k = 0; k < 6; ++k) a[k] = 0.f;
    }
    load_row6(ub, h0, w0, m);

    float pV[4], pSE[5], pSW[5];
    level_flux(a, m, pV, pSE, pSW, inv_k2);

#pragma unroll
    for (int r = 0; r < RSTRIP; ++r) {
        const int h = h0 + r;
        if (h + 1 < HGT) load_row6(ub, h + 1, w0, d);
        else {
#pragma unroll
            for (int k = 0; k < 6; ++k) d[k] = 0.f;
        }

        float hF[5];
#pragma unroll
        for (int i = 0; i < 5; ++i) hF[i] = pm_flux(m[i + 1] - m[i], inv_k2);

        float cV[4], cSE[5], cSW[5];
        level_flux(m, d, cV, cSE, cSW, inv_k2);

        float o[4];
#pragma unroll
        for (int j = 0; j < 4; ++j) {
            // +S -N +E -W, diagonals at weight 0.5 (signs from g evenness).
            float axial = cV[j] - pV[j] + hF[j + 1] - hF[j];
            float diag  = cSE[j + 1] + cSW[j] - pSE[j] - pSW[j + 1];
            float upd = fmaf(0.5f, diag, axial);
            o[j] = fmaf(delta, upd, m[j + 1]);
        }
        emit(h, make_float4(o[0], o[1], o[2], o[3]));

        // roll the window down one row
#pragma unroll
        for (int k = 0; k < 6; ++k) m[k] = d[k];
#pragma unroll
        for (int j = 0; j < 4; ++j) pV[j] = cV[j];
#pragma unroll
        for (int i = 0; i < 5; ++i) { pSE[i] = cSE[i]; pSW[i] = cSW[i]; }
    }
}

__device__ __forceinline__ void strip_coords(int idx, int& b, int& h0, int& w0) {
    b = idx / (STRIPS_H * WQ);
    int rem = idx - b * (STRIPS_H * WQ);
    int sh = rem / WQ;
    w0 = (rem - sh * WQ) * 4;
    h0 = sh * RSTRIP;
}

// ---------------------------------------------------------------------------
// Kernel 1: RGB -> luminance (vectorized). u batch stride = ubs.
// ---------------------------------------------------------------------------
__global__ void lum_v4(const float* __restrict__ x, float* __restrict__ u, int ubs) {
    int idx = blockIdx.x * blockDim.x + threadIdx.x;
    if (idx >= NQUAD) return;
    int b = idx / (PLANE / 4);
    int off = (idx - b * (PLANE / 4)) * 4;
    const float* xb = x + (size_t)b * BSTRIDE + off;
    float4 r = ld4(xb);
    float4 g = ld4(xb + PLANE);
    float4 bl = ld4(xb + 2 * PLANE);
    float4 v;
    v.x = 0.299f * r.x + 0.587f * g.x + 0.114f * bl.x;
    v.y = 0.299f * r.y + 0.587f * g.y + 0.114f * bl.y;
    v.z = 0.299f * r.z + 0.587f * g.z + 0.114f * bl.z;
    v.w = 0.299f * r.w + 0.587f * g.w + 0.114f * bl.w;
    st4(u + (size_t)b * ubs + off, v);
}

// ---------------------------------------------------------------------------
// Kernel 2: one PM step, strip form.
// ---------------------------------------------------------------------------
__global__ void pm_step_strip(const float* __restrict__ uin, float* __restrict__ uout,
                              int ubs,
                              const float* __restrict__ pdelta,
                              const float* __restrict__ pkappa) {
    int idx = blockIdx.x * blockDim.x + threadIdx.x;
    if (idx >= NSTRIPS) return;
    int b, h0, w0;
    strip_coords(idx, b, h0, w0);

    const float* ub = uin + (size_t)b * ubs;
    float* ob = uout + (size_t)b * ubs;

    float delta = *pdelta;
    float kappa = *pkappa;
    float inv_k2 = __builtin_amdgcn_rcpf(kappa * kappa);

    pm_strip(ub, h0, w0, delta, inv_k2,
             [&](int h, float4 v) { st4(ob + h * WID + w0, v); });
}

// ---------------------------------------------------------------------------
// Kernel 3: final PM step fused with channel expand; d_out write-only.
// ---------------------------------------------------------------------------
__global__ void pm_step_expand_strip(const float* __restrict__ uin, int ubs,
                                     float* __restrict__ out,
                                     const float* __restrict__ pdelta,
                                     const float* __restrict__ pkappa,
                                     const float* __restrict__ Wexp,
                                     const float* __restrict__ bexp) {
    int idx = blockIdx.x * blockDim.x + threadIdx.x;
    if (idx >= NSTRIPS) return;
    int b, h0, w0;
    strip_coords(idx, b, h0, w0);

    const float* ub = uin + (size_t)b * ubs;

    float delta = *pdelta;
    float kappa = *pkappa;
    float inv_k2 = __builtin_amdgcn_rcpf(kappa * kappa);

    float s0 = Wexp[0] + Wexp[1] + Wexp[2];
    float s1 = Wexp[3] + Wexp[4] + Wexp[5];
    float s2 = Wexp[6] + Wexp[7] + Wexp[8];
    float b0 = bexp[0], b1 = bexp[1], b2 = bexp[2];

    float* outb = out + (size_t)b * BSTRIDE;

    pm_strip(ub, h0, w0, delta, inv_k2, [&](int h, float4 u) {
        size_t ob = (size_t)h * WID + w0;
        st4(outb + ob,
            make_float4(s0 * u.x + b0, s0 * u.y + b0, s0 * u.z + b0, s0 * u.w + b0));
        st4(outb + ob + PLANE,
            make_float4(s1 * u.x + b1, s1 * u.y + b1, s1 * u.z + b1, s1 * u.w + b1));
        st4(outb + ob + 2 * PLANE,
            make_float4(s2 * u.x + b2, s2 * u.y + b2, s2 * u.z + b2, s2 * u.w + b2));
    });
}

// ---------------------------------------------------------------------------
// Fallback expand (ws too small): reads own pixel from plane 0, writes 3 planes.
// ---------------------------------------------------------------------------
__global__ void expand_own_v4(float* __restrict__ out,
                              const float* __restrict__ Wexp,
                              const float* __restrict__ bexp) {
    int idx = blockIdx.x * blockDim.x + threadIdx.x;
    if (idx >= NQUAD) return;
    int b = idx / (PLANE / 4);
    int off = (idx - b * (PLANE / 4)) * 4;
    size_t base = (size_t)b * BSTRIDE + off;

    float4 u = ld4(out + base);
    float s0 = Wexp[0] + Wexp[1] + Wexp[2];
    float s1 = Wexp[3] + Wexp[4] + Wexp[5];
    float s2 = Wexp[6] + Wexp[7] + Wexp[8];
    float b0 = bexp[0], b1 = bexp[1], b2 = bexp[2];

    st4(out + base, make_float4(s0 * u.x + b0, s0 * u.y + b0, s0 * u.z + b0, s0 * u.w + b0));
    st4(out + base + PLANE,
        make_float4(s1 * u.x + b1, s1 * u.y + b1, s1 * u.z + b1, s1 * u.w + b1));
    st4(out + base + 2 * PLANE,
        make_float4(s2 * u.x + b2, s2 * u.y + b2, s2 * u.z + b2, s2 * u.w + b2));
}

extern "C" void kernel_launch(void* const* d_in, const int* in_sizes, int n_in,
                              void* d_out, int out_size, void* d_ws, size_t ws_size,
                              hipStream_t stream) {
    const float* x      = (const float*)d_in[0];
    const float* pdelta = (const float*)d_in[1];
    const float* pkappa = (const float*)d_in[2];
    const float* Wexp   = (const float*)d_in[3];
    const float* bexp   = (const float*)d_in[4];
    float* out = (float*)d_out;

    const int block = 256;
    const int grid_q = (NQUAD + block - 1) / block;     // 8192 (lum/expand)
    const int grid_s = (NSTRIPS + block - 1) / block;   // 1024 (strip kernels)

    const size_t need = (size_t)2 * NPIX * sizeof(float);   // 64 MB
    if (ws_size >= need) {
        // Ping-pong u in d_ws; d_out written exactly once by the fused final step.
        float* uA = (float*)d_ws;
        float* uB = uA + NPIX;
        lum_v4<<<grid_q, block, 0, stream>>>(x, uA, PLANE);
        float* src = uA;
        float* dst = uB;
        for (int k = 0; k < 29; ++k) {
            pm_step_strip<<<grid_s, block, 0, stream>>>(src, dst, PLANE, pdelta, pkappa);
            float* t = src; src = dst; dst = t;
        }
        pm_step_expand_strip<<<grid_s, block, 0, stream>>>(src, PLANE, out,
                                                           pdelta, pkappa, Wexp, bexp);
    } else {
        // Fallback: ping-pong in d_out planes 0/1 (batch stride BSTRIDE).
        float* uA = out;
        float* uB = out + PLANE;
        lum_v4<<<grid_q, block, 0, stream>>>(x, uA, BSTRIDE);
        float* src = uA;
        float* dst = uB;
        for (int k = 0; k < 30; ++k) {
            pm_step_strip<<<grid_s, block, 0, stream>>>(src, dst, BSTRIDE, pdelta, pkappa);
            float* t = src; src = dst; dst = t;
        }
        expand_own_v4<<<grid_q, block, 0, stream>>>(out, Wexp, bexp);
    }
}

// Round 5
// 388.716 us; speedup vs baseline: 3.1280x; 1.1522x over previous
//
#include <hip/hip_runtime.h>

// Problem: x [32,3,512,512] fp32, 30 Perona-Malik iterations, expand to 3ch.
#define BATCH 32
#define HGT 512
#define WID 512
#define PLANE (HGT * WID)            // 262144
#define NPIX (BATCH * PLANE)         // 8388608
#define BSTRIDE (3 * PLANE)          // batch stride in x and d_out
#define WQ (WID / 4)                 // 128 col-quads per row
#define NQUAD (NPIX / 4)

// Fused-2 geometry: each block does 2 PM steps on a full-width row slab.
#define RSLAB 16                     // trusted output rows per block
#define SLABS (HGT / RSLAB)          // 32
#define LROWS (RSLAB + 4)            // 20 input rows (2-row halo each side)
#define BROWS (RSLAB + 2)            // 18 step-1 rows
#define FBLOCKS (BATCH * SLABS)      // 1024 blocks
#define FTHREADS 512                 // 4 row-strips x 128 quads
#define LDS_BYTES ((LROWS + BROWS) * WID * 4)   // 77824 B -> 2 blocks/CU

__device__ __forceinline__ float4 ld4(const float* p) {
    return *reinterpret_cast<const float4*>(p);
}
__device__ __forceinline__ void st4(float* p, float4 v) {
    *reinterpret_cast<float4*>(p) = v;
}

// phi(d) = d / (1 + d^2/k^2); g even in d -> undirected edge flux shared
// by both endpoint pixels with opposite signs.
__device__ __forceinline__ float pm_flux(float d, float ik2) {
    return d * __builtin_amdgcn_rcpf(fmaf(d * d, ik2, 1.f));
}

// 6-wide row segment from an LDS row buffer; cols outside image -> 0.
__device__ __forceinline__ void lds_row6(const float* __restrict__ buf, int row, int quad,
                                         float r[6]) {
    const float* p = buf + row * WID + (quad << 2);
    float4 v = ld4(p);
    r[1] = v.x; r[2] = v.y; r[3] = v.z; r[4] = v.w;
    r[0] = (quad > 0) ? p[-1] : 0.f;
    r[5] = (quad < WQ - 1) ? p[4] : 0.f;
}

// Shared fluxes between upper row a and lower row b.
__device__ __forceinline__ void level_flux(const float a[6], const float b[6],
                                           float vF[4], float seF[5], float swF[5],
                                           float ik2) {
#pragma unroll
    for (int j = 0; j < 4; ++j) vF[j] = pm_flux(b[j + 1] - a[j + 1], ik2);
#pragma unroll
    for (int i = 0; i < 5; ++i) seF[i] = pm_flux(b[i + 1] - a[i], ik2);
#pragma unroll
    for (int i = 0; i < 5; ++i) swF[i] = pm_flux(b[i] - a[i + 1], ik2);
}

// Rolling-row PM update over n contiguous rows [L0, L0+n) read from LDS buf.
// emit(L, result) per row. Reads rows L0-1 .. L0+n (must be in-buffer).
template <typename Emit>
__device__ __forceinline__ void strip_from_lds(const float* __restrict__ buf, int L0, int n,
                                               int quad, float delta, float ik2,
                                               Emit&& emit) {
    float a[6], m[6], d6[6];
    lds_row6(buf, L0 - 1, quad, a);
    lds_row6(buf, L0, quad, m);
    float pV[4], pSE[5], pSW[5];
    level_flux(a, m, pV, pSE, pSW, ik2);

    for (int i = 0; i < n; ++i) {
        lds_row6(buf, L0 + i + 1, quad, d6);
        float hF[5];
#pragma unroll
        for (int t = 0; t < 5; ++t) hF[t] = pm_flux(m[t + 1] - m[t], ik2);
        float cV[4], cSE[5], cSW[5];
        level_flux(m, d6, cV, cSE, cSW, ik2);
        float o[4];
#pragma unroll
        for (int j = 0; j < 4; ++j) {
            float axial = cV[j] - pV[j] + hF[j + 1] - hF[j];
            float diag  = cSE[j + 1] + cSW[j] - pSE[j] - pSW[j + 1];
            o[j] = fmaf(delta, fmaf(0.5f, diag, axial), m[j + 1]);
        }
        emit(L0 + i, make_float4(o[0], o[1], o[2], o[3]));
#pragma unroll
        for (int t = 0; t < 6; ++t) m[t] = d6[t];
#pragma unroll
        for (int j = 0; j < 4; ++j) pV[j] = cV[j];
#pragma unroll
        for (int t = 0; t < 5; ++t) { pSE[t] = cSE[t]; pSW[t] = cSW[t]; }
    }
}

// ---------------------------------------------------------------------------
// Fused kernel: 2 PM steps on one row slab.
// MODE 0: src = x (lum computed on load), dst = u.
// MODE 1: src = u, dst = u.
// MODE 2: src = u, dst = d_out base (expand: 3 planes).
// sstr/dstr are per-image strides of src/dst.
// ---------------------------------------------------------------------------
template <int MODE>
__global__ __launch_bounds__(FTHREADS, 4)
void pm_fused2(const float* __restrict__ src, int sstr,
               float* __restrict__ dst, int dstr,
               const float* __restrict__ pdelta, const float* __restrict__ pkappa,
               const float* __restrict__ Wexp, const float* __restrict__ bexp) {
    extern __shared__ float lds[];
    float* bufA = lds;                    // LROWS x WID
    float* bufB = lds + LROWS * WID;      // BROWS x WID

    const int img  = blockIdx.x >> 5;     // / SLABS
    const int slab = blockIdx.x & (SLABS - 1);
    const int H0   = slab * RSLAB;
    const int tid  = threadIdx.x;

    const float delta = *pdelta;
    const float kappa = *pkappa;
    const float ik2 = __builtin_amdgcn_rcpf(kappa * kappa);

    // ---- load LROWS rows into bufA (zero-fill rows outside image) ----
    const float* sb = src + (size_t)img * sstr;
#pragma unroll
    for (int i = tid; i < LROWS * WQ; i += FTHREADS) {
        int row  = i >> 7;                // / WQ
        int quad = i & (WQ - 1);
        int g = H0 - 2 + row;
        float4 v = make_float4(0.f, 0.f, 0.f, 0.f);
        if ((unsigned)g < (unsigned)HGT) {
            const float* p = sb + g * WID + (quad << 2);
            if (MODE == 0) {
                float4 r = ld4(p), gg = ld4(p + PLANE), bb = ld4(p + 2 * PLANE);
                v.x = fmaf(0.299f, r.x, fmaf(0.587f, gg.x, 0.114f * bb.x));
                v.y = fmaf(0.299f, r.y, fmaf(0.587f, gg.y, 0.114f * bb.y));
                v.z = fmaf(0.299f, r.z, fmaf(0.587f, gg.z, 0.114f * bb.z));
                v.w = fmaf(0.299f, r.w, fmaf(0.587f, gg.w, 0.114f * bb.w));
            } else {
                v = ld4(p);
            }
        }
        st4(bufA + row * WID + (quad << 2), v);
    }
    __syncthreads();

    const int strip = tid >> 7;           // 0..3
    const int quad  = tid & (WQ - 1);

    // ---- step 1: rows L in [1,19) -> bufB[L-1]; force 0 outside image ----
    {
        int L0 = 1 + 5 * strip - (strip == 3 ? 1 : 0);   // {1,6,11,15}
        int n  = (strip < 2) ? 5 : 4;                    // {5,5,4,4}
        strip_from_lds(bufA, L0, n, quad, delta, ik2, [&](int L, float4 o) {
            int g = H0 - 2 + L;
            if ((unsigned)g >= (unsigned)HGT) o = make_float4(0.f, 0.f, 0.f, 0.f);
            st4(bufB + (L - 1) * WID + (quad << 2), o);
        });
    }
    __syncthreads();

    // ---- step 2: bufB rows LB in [1,17) -> global rows H0..H0+15 ----
    float s0 = 0.f, s1 = 0.f, s2 = 0.f, b0 = 0.f, b1 = 0.f, b2 = 0.f;
    if (MODE == 2) {
        s0 = Wexp[0] + Wexp[1] + Wexp[2];
        s1 = Wexp[3] + Wexp[4] + Wexp[5];
        s2 = Wexp[6] + Wexp[7] + Wexp[8];
        b0 = bexp[0]; b1 = bexp[1]; b2 = bexp[2];
    }
    {
        int LB0 = 1 + 4 * strip;          // 4 rows per strip
        float* db = dst + (size_t)img * dstr;
        strip_from_lds(bufB, LB0, 4, quad, delta, ik2, [&](int LB, float4 o) {
            int g = H0 - 1 + LB;          // guaranteed in-image
            float* p = db + g * WID + (quad << 2);
            if (MODE == 2) {
                st4(p, make_float4(fmaf(s0, o.x, b0), fmaf(s0, o.y, b0),
                                   fmaf(s0, o.z, b0), fmaf(s0, o.w, b0)));
                st4(p + PLANE, make_float4(fmaf(s1, o.x, b1), fmaf(s1, o.y, b1),
                                           fmaf(s1, o.z, b1), fmaf(s1, o.w, b1)));
                st4(p + 2 * PLANE, make_float4(fmaf(s2, o.x, b2), fmaf(s2, o.y, b2),
                                               fmaf(s2, o.z, b2), fmaf(s2, o.w, b2)));
            } else {
                st4(p, o);
            }
        });
    }
}

// ---------------------------------------------------------------------------
// Fallback expand (ws too small): reads own pixel from plane 0, writes 3 planes.
// ---------------------------------------------------------------------------
__global__ void expand_own_v4(float* __restrict__ out,
                              const float* __restrict__ Wexp,
                              const float* __restrict__ bexp) {
    int idx = blockIdx.x * blockDim.x + threadIdx.x;
    if (idx >= NQUAD) return;
    int b = idx / (PLANE / 4);
    int off = (idx - b * (PLANE / 4)) * 4;
    size_t base = (size_t)b * BSTRIDE + off;

    float4 u = ld4(out + base);
    float s0 = Wexp[0] + Wexp[1] + Wexp[2];
    float s1 = Wexp[3] + Wexp[4] + Wexp[5];
    float s2 = Wexp[6] + Wexp[7] + Wexp[8];
    float b0 = bexp[0], b1 = bexp[1], b2 = bexp[2];

    st4(out + base, make_float4(s0 * u.x + b0, s0 * u.y + b0, s0 * u.z + b0, s0 * u.w + b0));
    st4(out + base + PLANE,
        make_float4(s1 * u.x + b1, s1 * u.y + b1, s1 * u.z + b1, s1 * u.w + b1));
    st4(out + base + 2 * PLANE,
        make_float4(s2 * u.x + b2, s2 * u.y + b2, s2 * u.z + b2, s2 * u.w + b2));
}

extern "C" void kernel_launch(void* const* d_in, const int* in_sizes, int n_in,
                              void* d_out, int out_size, void* d_ws, size_t ws_size,
                              hipStream_t stream) {
    const float* x      = (const float*)d_in[0];
    const float* pdelta = (const float*)d_in[1];
    const float* pkappa = (const float*)d_in[2];
    const float* Wexp   = (const float*)d_in[3];
    const float* bexp   = (const float*)d_in[4];
    float* out = (float*)d_out;

    const size_t need = (size_t)2 * NPIX * sizeof(float);   // 64 MB
    if (ws_size >= need) {
        // 15 fused launches: F1 = lum + steps 1-2; F2..F14 = steps 3-28;
        // F15 = steps 29-30 + channel expand (d_out written exactly once).
        float* uA = (float*)d_ws;
        float* uB = uA + NPIX;
        pm_fused2<0><<<FBLOCKS, FTHREADS, LDS_BYTES, stream>>>(
            x, BSTRIDE, uA, PLANE, pdelta, pkappa, Wexp, bexp);
        float* s = uA;
        float* d = uB;
        for (int k = 0; k < 13; ++k) {
            pm_fused2<1><<<FBLOCKS, FTHREADS, LDS_BYTES, stream>>>(
                s, PLANE, d, PLANE, pdelta, pkappa, Wexp, bexp);
            float* t = s; s = d; d = t;
        }
        pm_fused2<2><<<FBLOCKS, FTHREADS, LDS_BYTES, stream>>>(
            s, PLANE, out, BSTRIDE, pdelta, pkappa, Wexp, bexp);
    } else {
        // Fallback: ping-pong in d_out planes 0/1; separate expand.
        float* uA = out;
        float* uB = out + PLANE;
        pm_fused2<0><<<FBLOCKS, FTHREADS, LDS_BYTES, stream>>>(
            x, BSTRIDE, uA, BSTRIDE, pdelta, pkappa, Wexp, bexp);
        float* s = uA;
        float* d = uB;
        for (int k = 0; k < 14; ++k) {
            pm_fused2<1><<<FBLOCKS, FTHREADS, LDS_BYTES, stream>>>(
                s, BSTRIDE, d, BSTRIDE, pdelta, pkappa, Wexp, bexp);
            float* t = s; s = d; d = t;
        }
        const int block = 256;
        const int grid_q = (NQUAD + block - 1) / block;
        expand_own_v4<<<grid_q, block, 0, stream>>>(out, Wexp, bexp);
    }
}

// Round 6
// 375.861 us; speedup vs baseline: 3.2350x; 1.0342x over previous
//
#include <hip/hip_runtime.h>

// Problem: x [32,3,512,512] fp32, 30 Perona-Malik iterations, expand to 3ch.
#define BATCH 32
#define HGT 512
#define WID 512
#define PLANE (HGT * WID)            // 262144
#define NPIX (BATCH * PLANE)         // 8388608
#define BSTRIDE (3 * PLANE)          // batch stride in x and d_out
#define WQ (WID / 4)                 // 128 col-quads per row
#define NQUAD (NPIX / 4)

// In-place fused-k geometry: block owns a 16-row slab + k-row halo each side.
#define RSLAB 16
#define SLABS (HGT / RSLAB)          // 32
#define FBLOCKS (BATCH * SLABS)      // 1024
#define FT 512                       // 4 row-strips x 128 quads

__device__ __forceinline__ float4 ld4(const float* p) {
    return *reinterpret_cast<const float4*>(p);
}
__device__ __forceinline__ void st4(float* p, float4 v) {
    *reinterpret_cast<float4*>(p) = v;
}

// phi(d) = d / (1 + d^2/k^2); g even -> undirected edge flux shared with
// opposite signs by its two endpoint pixels.
__device__ __forceinline__ float pm_flux(float d, float ik2) {
    return d * __builtin_amdgcn_rcpf(fmaf(d * d, ik2, 1.f));
}

// 6-wide row segment from LDS row buffer; cols outside image -> 0.
__device__ __forceinline__ void lds_row6(const float* __restrict__ buf, int row, int quad,
                                         float r[6]) {
    const float* p = buf + row * WID + (quad << 2);
    float4 v = ld4(p);
    r[1] = v.x; r[2] = v.y; r[3] = v.z; r[4] = v.w;
    r[0] = (quad > 0) ? p[-1] : 0.f;
    r[5] = (quad < WQ - 1) ? p[4] : 0.f;
}

__device__ __forceinline__ void level_flux(const float a[6], const float b[6],
                                           float vF[4], float seF[5], float swF[5],
                                           float ik2) {
#pragma unroll
    for (int j = 0; j < 4; ++j) vF[j] = pm_flux(b[j + 1] - a[j + 1], ik2);
#pragma unroll
    for (int i = 0; i < 5; ++i) seF[i] = pm_flux(b[i + 1] - a[i], ik2);
#pragma unroll
    for (int i = 0; i < 5; ++i) swF[i] = pm_flux(b[i] - a[i + 1], ik2);
}

// Row range [L0,L1) split over 4 strips: strip t gets n rows starting s0.
__device__ __forceinline__ void srange(int L0, int L1, int strip, int& s0, int& n) {
    int tot = L1 - L0;
    int base = tot >> 2, rem = tot & 3;
    n = base + (strip < rem ? 1 : 0);
    s0 = L0 + strip * base + (strip < rem ? strip : rem);
}

// ---------------------------------------------------------------------------
// Fused-S kernel, in-place LDS trapezoid.
// MODE 0: src = x (lum on load). MODE 1: plain u -> u. MODE 2: final, expand
// into 3 output planes. LDS = (RSLAB + 2*S) rows x 512 cols.
// Per step s: valid rows [s, LR-s); compute rows [s+1, LR-1-s) into regs,
// barrier, write back (rows outside image forced to 0), barrier.
// Final step writes global directly (no LDS write -> no barriers).
// ---------------------------------------------------------------------------
template <int MODE, int S>
__global__ __launch_bounds__(FT, 4)
void pm_fusedk(const float* __restrict__ src, int sstr,
               float* __restrict__ dst, int dstr,
               const float* __restrict__ pdelta, const float* __restrict__ pkappa,
               const float* __restrict__ Wexp, const float* __restrict__ bexp) {
    constexpr int LR = RSLAB + 2 * S;
    extern __shared__ float buf[];            // LR x WID

    const int img   = blockIdx.x >> 5;        // / SLABS
    const int slab  = blockIdx.x & (SLABS - 1);
    const int H0    = slab * RSLAB;
    const int tid   = threadIdx.x;
    const int strip = tid >> 7;
    const int quad  = tid & (WQ - 1);

    const float delta = *pdelta;
    const float kappa = *pkappa;
    const float ik2 = __builtin_amdgcn_rcpf(kappa * kappa);

    // ---- load LR rows (rows outside image -> 0) ----
    const float* sb = src + (size_t)img * sstr;
#pragma unroll
    for (int i = tid; i < LR * WQ; i += FT) {
        int row = i >> 7;
        int q   = i & (WQ - 1);
        int g = H0 - S + row;
        float4 v = make_float4(0.f, 0.f, 0.f, 0.f);
        if ((unsigned)g < (unsigned)HGT) {
            const float* p = sb + g * WID + (q << 2);
            if (MODE == 0) {
                float4 r = ld4(p), gg = ld4(p + PLANE), bb = ld4(p + 2 * PLANE);
                v.x = fmaf(0.299f, r.x, fmaf(0.587f, gg.x, 0.114f * bb.x));
                v.y = fmaf(0.299f, r.y, fmaf(0.587f, gg.y, 0.114f * bb.y));
                v.z = fmaf(0.299f, r.z, fmaf(0.587f, gg.z, 0.114f * bb.z));
                v.w = fmaf(0.299f, r.w, fmaf(0.587f, gg.w, 0.114f * bb.w));
            } else {
                v = ld4(p);
            }
        }
        st4(buf + row * WID + (q << 2), v);
    }
    __syncthreads();

    float s0c = 0.f, s1c = 0.f, s2c = 0.f, b0c = 0.f, b1c = 0.f, b2c = 0.f;
    if (MODE == 2) {
        s0c = Wexp[0] + Wexp[1] + Wexp[2];
        s1c = Wexp[3] + Wexp[4] + Wexp[5];
        s2c = Wexp[6] + Wexp[7] + Wexp[8];
        b0c = bexp[0]; b1c = bexp[1]; b2c = bexp[2];
    }

    float* db = dst + (size_t)img * dstr;

#pragma unroll
    for (int s = 0; s < S; ++s) {
        const int L0r = s + 1, L1r = LR - 1 - s;
        int st0, n;
        srange(L0r, L1r, strip, st0, n);

        float4 res[6];
        float a[6], m[6], d6[6];
        lds_row6(buf, st0 - 1, quad, a);
        lds_row6(buf, st0, quad, m);
        float pV[4], pSE[5], pSW[5];
        level_flux(a, m, pV, pSE, pSW, ik2);

#pragma unroll
        for (int i = 0; i < 6; ++i) {
            if (i < n) {
                lds_row6(buf, st0 + i + 1, quad, d6);
                float hF[5];
#pragma unroll
                for (int t = 0; t < 5; ++t) hF[t] = pm_flux(m[t + 1] - m[t], ik2);
                float cV[4], cSE[5], cSW[5];
                level_flux(m, d6, cV, cSE, cSW, ik2);
                float o[4];
#pragma unroll
                for (int j = 0; j < 4; ++j) {
                    float axial = cV[j] - pV[j] + hF[j + 1] - hF[j];
                    float diag  = cSE[j + 1] + cSW[j] - pSE[j] - pSW[j + 1];
                    o[j] = fmaf(delta, fmaf(0.5f, diag, axial), m[j + 1]);
                }
                int g = H0 - S + st0 + i;
                bool in = (unsigned)g < (unsigned)HGT;
                res[i] = in ? make_float4(o[0], o[1], o[2], o[3])
                            : make_float4(0.f, 0.f, 0.f, 0.f);
#pragma unroll
                for (int t = 0; t < 6; ++t) m[t] = d6[t];
#pragma unroll
                for (int j = 0; j < 4; ++j) pV[j] = cV[j];
#pragma unroll
                for (int t = 0; t < 5; ++t) { pSE[t] = cSE[t]; pSW[t] = cSW[t]; }
            }
        }

        if (s == S - 1) {
            // Final step: rows g = H0..H0+15, write global directly.
#pragma unroll
            for (int i = 0; i < 6; ++i) {
                if (i < n) {
                    int g = H0 - S + st0 + i;
                    float* p = db + g * WID + (quad << 2);
                    if (MODE == 2) {
                        float4 u = res[i];
                        st4(p, make_float4(fmaf(s0c, u.x, b0c), fmaf(s0c, u.y, b0c),
                                           fmaf(s0c, u.z, b0c), fmaf(s0c, u.w, b0c)));
                        st4(p + PLANE,
                            make_float4(fmaf(s1c, u.x, b1c), fmaf(s1c, u.y, b1c),
                                        fmaf(s1c, u.z, b1c), fmaf(s1c, u.w, b1c)));
                        st4(p + 2 * PLANE,
                            make_float4(fmaf(s2c, u.x, b2c), fmaf(s2c, u.y, b2c),
                                        fmaf(s2c, u.z, b2c), fmaf(s2c, u.w, b2c)));
                    } else {
                        st4(p, res[i]);
                    }
                }
            }
        } else {
            __syncthreads();
#pragma unroll
            for (int i = 0; i < 6; ++i)
                if (i < n) st4(buf + (st0 + i) * WID + (quad << 2), res[i]);
            __syncthreads();
        }
    }
}

// ---------------------------------------------------------------------------
// Fallback expand: reads u from usrc (own pixel), writes 3 planes of out.
// ---------------------------------------------------------------------------
__global__ void expand_from(const float* __restrict__ usrc, int ustr,
                            float* __restrict__ out,
                            const float* __restrict__ Wexp,
                            const float* __restrict__ bexp) {
    int idx = blockIdx.x * blockDim.x + threadIdx.x;
    if (idx >= NQUAD) return;
    int b = idx / (PLANE / 4);
    int off = (idx - b * (PLANE / 4)) * 4;

    float4 u = ld4(usrc + (size_t)b * ustr + off);
    float s0 = Wexp[0] + Wexp[1] + Wexp[2];
    float s1 = Wexp[3] + Wexp[4] + Wexp[5];
    float s2 = Wexp[6] + Wexp[7] + Wexp[8];
    float b0 = bexp[0], b1 = bexp[1], b2 = bexp[2];

    size_t base = (size_t)b * BSTRIDE + off;
    st4(out + base, make_float4(fmaf(s0, u.x, b0), fmaf(s0, u.y, b0),
                                fmaf(s0, u.z, b0), fmaf(s0, u.w, b0)));
    st4(out + base + PLANE, make_float4(fmaf(s1, u.x, b1), fmaf(s1, u.y, b1),
                                        fmaf(s1, u.z, b1), fmaf(s1, u.w, b1)));
    st4(out + base + 2 * PLANE, make_float4(fmaf(s2, u.x, b2), fmaf(s2, u.y, b2),
                                            fmaf(s2, u.z, b2), fmaf(s2, u.w, b2)));
}

extern "C" void kernel_launch(void* const* d_in, const int* in_sizes, int n_in,
                              void* d_out, int out_size, void* d_ws, size_t ws_size,
                              hipStream_t stream) {
    const float* x      = (const float*)d_in[0];
    const float* pdelta = (const float*)d_in[1];
    const float* pkappa = (const float*)d_in[2];
    const float* Wexp   = (const float*)d_in[3];
    const float* bexp   = (const float*)d_in[4];
    float* out = (float*)d_out;

    const int LDS4 = (RSLAB + 8) * WID * 4;   // 49152 B
    const int LDS2 = (RSLAB + 4) * WID * 4;   // 40960 B

    const size_t need = (size_t)2 * NPIX * sizeof(float);   // 64 MB
    if (ws_size >= need) {
        // 8 dispatches: [lum+steps1-4], 6x[4 steps] (5-28), [steps29-30+expand].
        float* uA = (float*)d_ws;
        float* uB = uA + NPIX;
        pm_fusedk<0, 4><<<FBLOCKS, FT, LDS4, stream>>>(
            x, BSTRIDE, uA, PLANE, pdelta, pkappa, Wexp, bexp);
        float* s = uA;
        float* d = uB;
        for (int k = 0; k < 6; ++k) {
            pm_fusedk<1, 4><<<FBLOCKS, FT, LDS4, stream>>>(
                s, PLANE, d, PLANE, pdelta, pkappa, Wexp, bexp);
            float* t = s; s = d; d = t;
        }
        // u28 is in s (= uA). Final 2 steps + expand, d_out written once.
        pm_fusedk<2, 2><<<FBLOCKS, FT, LDS2, stream>>>(
            s, PLANE, out, BSTRIDE, pdelta, pkappa, Wexp, bexp);
    } else {
        // Fallback: ping-pong in d_out planes 0/1, separate expand.
        float* uA = out;            // plane 0
        float* uB = out + PLANE;    // plane 1
        pm_fusedk<0, 4><<<FBLOCKS, FT, LDS4, stream>>>(
            x, BSTRIDE, uA, BSTRIDE, pdelta, pkappa, Wexp, bexp);
        float* s = uA;
        float* d = uB;
        for (int k = 0; k < 6; ++k) {
            pm_fusedk<1, 4><<<FBLOCKS, FT, LDS4, stream>>>(
                s, BSTRIDE, d, BSTRIDE, pdelta, pkappa, Wexp, bexp);
            float* t = s; s = d; d = t;
        }
        // u28 in plane0; 2 more steps into plane1, then expand from plane1.
        pm_fusedk<1, 2><<<FBLOCKS, FT, LDS2, stream>>>(
            s, BSTRIDE, d, BSTRIDE, pdelta, pkappa, Wexp, bexp);
        const int block = 256;
        const int grid_q = (NQUAD + block - 1) / block;
        expand_from<<<grid_q, block, 0, stream>>>(d, BSTRIDE, out, Wexp, bexp);
    }
}